// Round 9
// baseline (446.851 us; speedup 1.0000x reference)
//
#include <hip/hip_runtime.h>

typedef unsigned short u16;
typedef unsigned int u32;
typedef unsigned long long u64;

#define B_TOTAL 65536
#define H 512
#define D 64
#define BM 64

typedef __bf16 bf16x8 __attribute__((ext_vector_type(8)));
typedef float f32x4 __attribute__((ext_vector_type(4)));

__device__ __forceinline__ u32 f2b(float f) {  // fp32 -> bf16 bits, RNE
  u32 u = __builtin_bit_cast(u32, f);
  return (u + 0x7fffu + ((u >> 16) & 1u)) >> 16;
}
__device__ __forceinline__ float b2f(u32 bits) {
  return __builtin_bit_cast(float, bits << 16);
}

// ---- workspace layout (bf16 element offsets) ----
// Weight regions are FRAGMENT-PACKED: for logical B-matrix M[NN][KK],
// packed[( (n>>4)*(KK/32) + (k>>5) )*512 + lane*8 + j] = M[n][k],
// n = ntile*16 + (lane&15), k = kstep*32 + (lane>>4)*8 + j.
#define OFF_Wz0b 0          /* [N=512][K=64]  fwd L0 */
#define OFF_Wx0b 32768
#define OFF_Wx1b 65536
#define OFF_Wx2b 98304
#define OFF_Wz1b 131072     /* [N=512][K=512] fwd */
#define OFF_Wz2b 393216
#define OFF_Wz3b 655360
#define OFF_Wz1t 917504     /* [N=512][K=512] transposed, bwd */
#define OFF_Wz2t 1179648
#define OFF_Wz3t 1441792
#define OFF_Wz0t 1703936    /* [N=64][K=512] transposed grad weights */
#define OFF_Wx0t 1736704
#define OFF_Wx1t 1769472
#define OFF_Wx2t 1802240
#define OFF_WEND 1835008
// Slabs deleted in R9 (sigmoids live in registers); workspace is weights only.
#define WS_ELEMS OFF_WEND

// ---- weight prep: fp32 -> bf16, fragment-packed (+ transposed variants) ----
__global__ __launch_bounds__(256) void prep_kernel(
    const float* __restrict__ Wz0, const float* __restrict__ Wz1,
    const float* __restrict__ Wz2, const float* __restrict__ Wz3,
    const float* __restrict__ Wx0, const float* __restrict__ Wx1,
    const float* __restrict__ Wx2, u16* __restrict__ wsb) {
  int i = blockIdx.x * 256 + threadIdx.x;   // grid exactly covers OFF_WEND
  const float* src;
  int NN, KK, trans, p;
  if (i < 131072) {                          // x-path fwd: [512][64] direct
    int r = i >> 15; p = i & 32767;
    src = (r == 0) ? Wz0 : (r == 1) ? Wx0 : (r == 2) ? Wx1 : Wx2;
    NN = 512; KK = 64; trans = 0;
  } else if (i < 917504) {                   // H fwd: [512][512] direct
    int j = i - 131072; int r = j >> 18; p = j & 262143;
    src = (r == 0) ? Wz1 : (r == 1) ? Wz2 : Wz3;
    NN = 512; KK = 512; trans = 0;
  } else if (i < 1703936) {                  // H bwd: transposed
    int j = i - 917504; int r = j >> 18; p = j & 262143;
    src = (r == 0) ? Wz1 : (r == 1) ? Wz2 : Wz3;
    NN = 512; KK = 512; trans = 1;
  } else {                                   // grad weights: [64][512] = W^T
    int j = i - 1703936; int r = j >> 15; p = j & 32767;
    src = (r == 0) ? Wz0 : (r == 1) ? Wx0 : (r == 2) ? Wx1 : Wx2;
    NN = 64; KK = 512; trans = 1;
  }
  int jj = p & 7, lane = (p >> 3) & 63, blk = p >> 9;
  int kt_sh = (KK == 64) ? 1 : 4;            // log2(KK/32)
  int ntile = blk >> kt_sh;
  int kstep = blk & ((1 << kt_sh) - 1);
  int n = ntile * 16 + (lane & 15);
  int k = kstep * 32 + ((lane >> 4) << 3) + jj;
  float v = trans ? src[k * NN + n] : src[n * KK + k];
  wsb[i] = (u16)f2b(v);
}

__global__ __launch_bounds__(256) void fill_sentinel(float* out, int n) {
  int i = blockIdx.x * 256 + threadIdx.x;
  if (i < n) out[i] = 12345.0f;   // unmistakable "workspace too small" marker
}

// ---- fully-fused ICNN fwd+bwd (single GEMM kernel) ----
// ROUND-9 = ROUND-8 (396us, correct) + REGISTER-RESIDENT SIGMOIDS:
// bwd_epi read the slab at exactly the (mt,nt,lane) index the SAME thread
// wrote in fwd_epi -- the slab round-trip through HBM was a hand-written
// register spill (384 MB traffic ~ 61us + store/load + addr math in every
// epilogue). Replaced by 3 per-thread arrays u64 sg[8] (4 bf16 sigmoids
// per u64; 16 VGPRs/layer, 48 total). All indexing compile-time via full
// unroll. R8 measured VGPR_Count=64 -> 64 regs of headroom under the 128
// cap; peak live ~126. Tripwire: traffic rising = spill.
// Carried from R8: B weights stream global->VGPR (L2-resident, depth-1
// rotation), ping-pong K-major zbuf (conflict-free ldA), 8 LDS-only
// barriers, col-split ownership (wave w: cols [w*32,+32), acc[4][2]).
// LDS = 2x64K zbuf + 9.2K xbuf = 137 KB, 1 block/CU, 16 waves.
__global__ __launch_bounds__(1024, 4) void icnn_kernel(
    const float* __restrict__ state,
    const float* __restrict__ bz0, const float* __restrict__ bx0,
    const float* __restrict__ bx1, const float* __restrict__ bx2,
    const float* __restrict__ WzL, const float* __restrict__ WxL,
    u16* __restrict__ wsw, float* __restrict__ out) {
  __shared__ u16 zbA[BM * H];       // K-major activations, ping  (64 KB)
  __shared__ u16 zbB[BM * H];       // K-major activations, pong  (64 KB)
  __shared__ u16 xbuf[BM * 72];     // padded x staging, 9.2 KB

  const int tid = threadIdx.x;
  const int w = tid >> 6;           // 0..15
  const int lane = tid & 63;
  const int l15 = lane & 15;
  const int q = lane >> 4;
  const int blk = blockIdx.x;

  const u16* Wz0b = wsw + OFF_Wz0b;
  const u16* Wx0b = wsw + OFF_Wx0b;
  const u16* Wx1b = wsw + OFF_Wx1b;
  const u16* Wx2b = wsw + OFF_Wx2b;
  const u16* Wz1b = wsw + OFF_Wz1b;
  const u16* Wz2b = wsw + OFF_Wz2b;
  const u16* Wz3b = wsw + OFF_Wz3b;
  const u16* Wz1t = wsw + OFF_Wz1t;
  const u16* Wz2t = wsw + OFF_Wz2t;
  const u16* Wz3t = wsw + OFF_Wz3t;
  const u16* Wz0t = wsw + OFF_Wz0t;
  const u16* Wx0t = wsw + OFF_Wx0t;
  const u16* Wx1t = wsw + OFF_Wx1t;
  const u16* Wx2t = wsw + OFF_Wx2t;

  // LDS-only barrier: orders zbuf ds ops across waves; global loads/stores
  // stay in flight across it (no vmcnt drain).
  auto lbar = [&]() {
    asm volatile("s_waitcnt lgkmcnt(0)" ::: "memory");
    __builtin_amdgcn_s_barrier();
    asm volatile("" ::: "memory");
  };

  // ---- stage x = state-1 into xbuf (bf16, padded row-major) ----
  {
    int r = tid >> 4, c0 = (tid & 15) << 2;  // 64 rows x 16 chunks of 4 floats
    const float* p = state + (blk * BM + r) * D + c0;
    f32x4 v = __builtin_nontemporal_load((const f32x4*)p);
    u32* dst = (u32*)&xbuf[r * 72 + c0];
    dst[0] = f2b(v[0] - 1.0f) | (f2b(v[1] - 1.0f) << 16);
    dst[1] = f2b(v[2] - 1.0f) | (f2b(v[3] - 1.0f) << 16);
  }

  f32x4 acc[4][2];                  // 32 acc regs: 64 rows x 32 cols / wave
  const f32x4 Z = {0.f, 0.f, 0.f, 0.f};
  f32x4 pk = Z;                     // grad park: wave's single 16x16 out tile
  u64 sg0[8], sg1[8], sg2[8];       // register-resident sigmoids, 48 VGPRs

  // K-major zbuf reads: A-frag (row tile mt, K-step st): lane(q,l15) needs
  // z[mt*16+l15][st*32+q*8..+8] -> offset (st*4+mt)*512 + q*128 + l15*8.
  // 64 lanes cover one contiguous 1KB span: zero bank conflicts.
  auto ldA = [&](const u16* zb, int mt, int step) -> bf16x8 {
    return *(const bf16x8*)(&zb[(step * 4 + mt) * 512 + q * 128 + l15 * 8]);
  };
  auto ldX = [&](int mt, int ks) -> bf16x8 {       // x A-frag from padded xbuf
    return *(const bf16x8*)(&xbuf[(mt * 16 + l15) * 72 + ks * 32 + q * 8]);
  };
  auto wrZ = [&](u16* zb, int row, int n, u16 bits) {  // K-major scatter write
    zb[((n >> 5) * 4 + (row >> 4)) * 512 + ((n >> 3) & 3) * 128 +
       (row & 15) * 8 + (n & 7)] = bits;
  };

  // acc = x @ Wx^T (K=64), zero-start. Wx streams global->VGPR.
  auto fwdX = [&](const u16* Wxp) {
    const u16* xb = Wxp + lane * 8;
#pragma unroll
    for (int ks = 0; ks < 2; ++ks) {
      bf16x8 b2[2];
#pragma unroll
      for (int nt = 0; nt < 2; ++nt)
        b2[nt] = *(const bf16x8*)(xb + ((w * 2 + nt) * 2 + ks) * 512);
#pragma unroll
      for (int mt = 0; mt < 4; ++mt) {
        bf16x8 ax = ldX(mt, ks);
#pragma unroll
        for (int nt = 0; nt < 2; ++nt) {
          f32x4 c = (ks == 0) ? Z : acc[mt][nt];
          acc[mt][nt] = __builtin_amdgcn_mfma_f32_16x16x32_bf16(ax, b2[nt], c, 0, 0, 0);
        }
      }
    }
  };

  // acc (+)= zb @ W^T (K=512). B streams global->VGPR with depth-1
  // rotation: bn (next step) issues before this step's MFMAs, so the
  // compiler's vmcnt wait on bc lands a full iteration after issue.
  auto fwdH = [&](const u16* Wp, const u16* zb, bool zero) {
    const u16* gb = Wp + (w * 2 * 16) * 512 + lane * 8;
    bf16x8 bc0 = *(const bf16x8*)(gb);
    bf16x8 bc1 = *(const bf16x8*)(gb + 16 * 512);
#pragma unroll 1
    for (int st = 0; st < 16; ++st) {
      int stn = (st < 15) ? st + 1 : st;     // clamp: harmless re-read at tail
      bf16x8 bn0 = *(const bf16x8*)(gb + stn * 512);
      bf16x8 bn1 = *(const bf16x8*)(gb + (16 + stn) * 512);
      bf16x8 a[4];
#pragma unroll
      for (int mt = 0; mt < 4; ++mt) a[mt] = ldA(zb, mt, st);
#pragma unroll
      for (int mt = 0; mt < 4; ++mt)
        acc[mt][0] = __builtin_amdgcn_mfma_f32_16x16x32_bf16(
            a[mt], bc0, (zero && st == 0) ? Z : acc[mt][0], 0, 0, 0);
#pragma unroll
      for (int mt = 0; mt < 4; ++mt)
        acc[mt][1] = __builtin_amdgcn_mfma_f32_16x16x32_bf16(
            a[mt], bc1, (zero && st == 0) ? Z : acc[mt][1], 0, 0, 0);
      bc0 = bn0; bc1 = bn1;
    }
  };

  // forward epilogue: a+=bias; z=softplus -> zb; s=sigmoid -> sg (registers)
  auto fwd_epi = [&](const float* biasp, u64 (&sg)[8], u16* zb) {
    float bias[2];
#pragma unroll
    for (int nt = 0; nt < 2; ++nt) bias[nt] = biasp[(w * 2 + nt) * 16 + l15];
#pragma unroll
    for (int mt = 0; mt < 4; ++mt)
#pragma unroll
      for (int nt = 0; nt < 2; ++nt) {
        int n = (w * 2 + nt) * 16 + l15;
        f32x4 A = acc[mt][nt];
        u64 pack = 0;
#pragma unroll
        for (int r = 0; r < 4; ++r) {
          float a = A[r] + bias[nt];
          float t = __expf(-a);
          float u = 1.0f + t;
          float s = __builtin_amdgcn_rcpf(u);     // sigmoid(a)
          float z = a + __logf(u);                // softplus(a)
          pack |= (u64)f2b(s) << (16 * r);
          wrZ(zb, mt * 16 + q * 4 + r, n, (u16)f2b(z));
        }
        sg[mt * 2 + nt] = pack;                   // static index (full unroll)
      }
  };
  auto d3_epi = [&](const float* biasp, u16* zb) {  // d3 = WzL*sigmoid(a3)
    float bias[2], wl[2];
#pragma unroll
    for (int nt = 0; nt < 2; ++nt) {
      bias[nt] = biasp[(w * 2 + nt) * 16 + l15];
      wl[nt] = WzL[(w * 2 + nt) * 16 + l15];
    }
#pragma unroll
    for (int mt = 0; mt < 4; ++mt)
#pragma unroll
      for (int nt = 0; nt < 2; ++nt) {
        int n = (w * 2 + nt) * 16 + l15;
        f32x4 A = acc[mt][nt];
#pragma unroll
        for (int r = 0; r < 4; ++r) {
          float a = A[r] + bias[nt];
          float t = __expf(-a);
          float s = __builtin_amdgcn_rcpf(1.0f + t);
          wrZ(zb, mt * 16 + q * 4 + r, n, (u16)f2b(wl[nt] * s));
        }
      }
  };
  // d = g * s -> zb (s from registers; same thread produced both)
  auto bwd_epi = [&](const u64 (&sg)[8], u16* zb) {
#pragma unroll
    for (int mt = 0; mt < 4; ++mt)
#pragma unroll
      for (int nt = 0; nt < 2; ++nt) {
        int n = (w * 2 + nt) * 16 + l15;
        f32x4 A = acc[mt][nt];
        u64 v = sg[mt * 2 + nt];                  // static index
#pragma unroll
        for (int r = 0; r < 4; ++r) {
          float s = b2f((u32)(v >> (16 * r)) & 0xffffu);
          wrZ(zb, mt * 16 + q * 4 + r, n, (u16)f2b(A[r] * s));
        }
      }
  };

  // grad mini-phase: pk += zb(d) @ Wg (main acc is DEAD here).
  // 16 waves <-> 16 out tiles: wave w owns tile (rt=w&3, ct=w>>2).
  // unroll 4: caps hoisted g-loads at 4 frags (full unroll spilled in R5).
  auto minigrad = [&](const u16* Wg, const u16* zb, bool init) {
    int rt = w & 3, ct = w >> 2;
    const u16* gb = Wg + lane * 8;
    f32x4 t = init ? Z : pk;
#pragma unroll 4
    for (int st = 0; st < 16; ++st) {
      bf16x8 a = ldA(zb, rt, st);
      bf16x8 g = *(const bf16x8*)(gb + (ct * 16 + st) * 512);
      t = __builtin_amdgcn_mfma_f32_16x16x32_bf16(a, g, t, 0, 0, 0);
    }
    pk = t;
  };

  // ---------------- forward ----------------
  lbar();                                   // xbuf ready
  fwdX(Wz0b);                               // a0 = x@Wz0^T
  fwd_epi(bz0, sg0, zbA);                   // z0 -> zbA, s0 -> regs
  lbar();                                   // P0
  fwdX(Wx0b); fwdH(Wz1b, zbA, false);       // a1 = x@Wx0^T + z0@Wz1^T
  fwd_epi(bx0, sg1, zbB);                   // z1 -> zbB (zbA still readable)
  lbar();                                   // P1
  fwdX(Wx1b); fwdH(Wz2b, zbB, false);       // a2
  fwd_epi(bx1, sg2, zbA);                   // z2 -> zbA
  lbar();                                   // P2
  fwdX(Wx2b); fwdH(Wz3b, zbA, false);       // a3
  d3_epi(bx2, zbB);                         // d3 -> zbB
  lbar();                                   // P3
  // ---------------- backward ----------------
  minigrad(Wx2t, zbB, true);                // pk  = d3@Wx2t
  fwdH(Wz3t, zbB, true);                    // acc = d3@Wz3
  bwd_epi(sg2, zbA);                        // d2 -> zbA
  lbar();                                   // P4
  minigrad(Wx1t, zbA, false);               // pk += d2@Wx1t
  fwdH(Wz2t, zbA, true);                    // acc = d2@Wz2
  bwd_epi(sg1, zbB);                        // d1 -> zbB
  lbar();                                   // P5
  minigrad(Wx0t, zbB, false);               // pk += d1@Wx0t
  fwdH(Wz1t, zbB, true);                    // acc = d1@Wz1
  bwd_epi(sg0, zbA);                        // d0 -> zbA
  lbar();                                   // P6
  // ---- final: out = d0@Wz0t + pk + WxL ----
  minigrad(Wz0t, zbA, false);               // pk += d0@Wz0t
  {
    int rt = w & 3, ct = w >> 2;
    float wx = WxL[ct * 16 + l15];
#pragma unroll
    for (int r = 0; r < 4; ++r) {
      int row = blk * BM + rt * 16 + q * 4 + r;
      out[row * D + ct * 16 + l15] = pk[r] + wx;
    }
  }
}

extern "C" void kernel_launch(void* const* d_in, const int* in_sizes, int n_in,
                              void* d_out, int out_size, void* d_ws, size_t ws_size,
                              hipStream_t stream) {
  const float* state = (const float*)d_in[0];
  const float* Wz0 = (const float*)d_in[1];
  const float* bz0 = (const float*)d_in[2];
  const float* Wz1 = (const float*)d_in[3];
  const float* Wz2 = (const float*)d_in[4];
  const float* Wz3 = (const float*)d_in[5];
  const float* WzL = (const float*)d_in[6];
  const float* Wx0 = (const float*)d_in[7];
  const float* bx0 = (const float*)d_in[8];
  const float* Wx1 = (const float*)d_in[9];
  const float* bx1 = (const float*)d_in[10];
  const float* Wx2 = (const float*)d_in[11];
  const float* bx2 = (const float*)d_in[12];
  const float* WxL = (const float*)d_in[13];

  if (ws_size < (size_t)WS_ELEMS * 2) {
    fill_sentinel<<<(out_size + 255) / 256, 256, 0, stream>>>((float*)d_out, out_size);
    return;
  }
  u16* wsw = (u16*)d_ws;
  prep_kernel<<<OFF_WEND / 256, 256, 0, stream>>>(Wz0, Wz1, Wz2, Wz3, Wx0, Wx1, Wx2, wsw);
  icnn_kernel<<<B_TOTAL / BM, 1024, 0, stream>>>(state, bz0, bx0, bx1, bx2, WzL, WxL,
                                                 wsw, (float*)d_out);
}

// Round 10
// 438.127 us; speedup vs baseline: 1.0199x; 1.0199x over previous
//
#include <hip/hip_runtime.h>

typedef unsigned short u16;
typedef unsigned int u32;
typedef unsigned long long u64;

#define B_TOTAL 65536
#define H 512
#define D 64
#define BM 64

typedef __bf16 bf16x8 __attribute__((ext_vector_type(8)));
typedef float f32x4 __attribute__((ext_vector_type(4)));

__device__ __forceinline__ u32 f2b(float f) {  // fp32 -> bf16 bits, RNE (sw)
  u32 u = __builtin_bit_cast(u32, f);
  return (u + 0x7fffu + ((u >> 16) & 1u)) >> 16;
}
__device__ __forceinline__ u16 f2bc(float f) { // fp32 -> bf16 bits via HW cvt
  return __builtin_bit_cast(u16, (__bf16)f);   // RNE; compiler pairs into
}                                              // v_cvt_pk_bf16_f32
__device__ __forceinline__ float b2f(u32 bits) {
  return __builtin_bit_cast(float, bits << 16);
}

// ---- workspace layout (bf16 element offsets) ----
// Weight regions are FRAGMENT-PACKED: for logical B-matrix M[NN][KK],
// packed[( (n>>4)*(KK/32) + (k>>5) )*512 + lane*8 + j] = M[n][k],
// n = ntile*16 + (lane&15), k = kstep*32 + (lane>>4)*8 + j.
#define OFF_Wz0b 0          /* [N=512][K=64]  fwd L0 */
#define OFF_Wx0b 32768
#define OFF_Wx1b 65536
#define OFF_Wx2b 98304
#define OFF_Wz1b 131072     /* [N=512][K=512] fwd */
#define OFF_Wz2b 393216
#define OFF_Wz3b 655360
#define OFF_Wz1t 917504     /* [N=512][K=512] transposed, bwd */
#define OFF_Wz2t 1179648
#define OFF_Wz3t 1441792
#define OFF_Wz0t 1703936    /* [N=64][K=512] transposed grad weights */
#define OFF_Wx0t 1736704
#define OFF_Wx1t 1769472
#define OFF_Wx2t 1802240
#define OFF_WEND 1835008
// Slabs deleted in R9 (sigmoids live in registers); workspace is weights only.
#define WS_ELEMS OFF_WEND

// ---- weight prep: fp32 -> bf16, fragment-packed (+ transposed variants) ----
__global__ __launch_bounds__(256) void prep_kernel(
    const float* __restrict__ Wz0, const float* __restrict__ Wz1,
    const float* __restrict__ Wz2, const float* __restrict__ Wz3,
    const float* __restrict__ Wx0, const float* __restrict__ Wx1,
    const float* __restrict__ Wx2, u16* __restrict__ wsb) {
  int i = blockIdx.x * 256 + threadIdx.x;   // grid exactly covers OFF_WEND
  const float* src;
  int NN, KK, trans, p;
  if (i < 131072) {                          // x-path fwd: [512][64] direct
    int r = i >> 15; p = i & 32767;
    src = (r == 0) ? Wz0 : (r == 1) ? Wx0 : (r == 2) ? Wx1 : Wx2;
    NN = 512; KK = 64; trans = 0;
  } else if (i < 917504) {                   // H fwd: [512][512] direct
    int j = i - 131072; int r = j >> 18; p = j & 262143;
    src = (r == 0) ? Wz1 : (r == 1) ? Wz2 : Wz3;
    NN = 512; KK = 512; trans = 0;
  } else if (i < 1703936) {                  // H bwd: transposed
    int j = i - 917504; int r = j >> 18; p = j & 262143;
    src = (r == 0) ? Wz1 : (r == 1) ? Wz2 : Wz3;
    NN = 512; KK = 512; trans = 1;
  } else {                                   // grad weights: [64][512] = W^T
    int j = i - 1703936; int r = j >> 15; p = j & 32767;
    src = (r == 0) ? Wz0 : (r == 1) ? Wx0 : (r == 2) ? Wx1 : Wx2;
    NN = 64; KK = 512; trans = 1;
  }
  int jj = p & 7, lane = (p >> 3) & 63, blk = p >> 9;
  int kt_sh = (KK == 64) ? 1 : 4;            // log2(KK/32)
  int ntile = blk >> kt_sh;
  int kstep = blk & ((1 << kt_sh) - 1);
  int n = ntile * 16 + (lane & 15);
  int k = kstep * 32 + ((lane >> 4) << 3) + jj;
  float v = trans ? src[k * NN + n] : src[n * KK + k];
  wsb[i] = (u16)f2b(v);
}

__global__ __launch_bounds__(256) void fill_sentinel(float* out, int n) {
  int i = blockIdx.x * 256 + threadIdx.x;
  if (i < n) out[i] = 12345.0f;   // unmistakable "workspace too small" marker
}

// ---- fully-fused ICNN fwd+bwd (single GEMM kernel) ----
// ROUND-10 = ROUND-9 (396us, correct, compute-issue-bound: MFMA 27% +
// VALU 48%, HBM 14%) + three VALU-pipe cuts:
//  (1) HW bf16 conversion: f2b (3 ALU ops/value) -> (__bf16) casts; the
//      compiler pairs them into v_cvt_pk_bf16_f32 (~250 values/thread).
//  (2) fwdH `unroll 2`: period-2 register renaming kills the bc=bn
//      rotation movs (#pragma unroll 1 forced ~8 v_mov x 16 steps x 7
//      calls = ~900 movs/thread).
//  (3) fwdH always accumulates; explicit zeroAcc() at the 3 bwd call
//      sites replaces the runtime (zero && st==0) select that the
//      un-unrolled loop couldn't constant-fold.
// Carried: B weights stream global->VGPR (L2-resident), register-resident
// sigmoids sg0..2 (no slabs), ping-pong K-major zbuf (conflict-free ldA),
// 8 LDS-only barriers, col-split ownership (wave w: cols [w*32,+32),
// acc[4][2]). LDS = 2x64K zbuf + 9.2K xbuf = 137 KB, 1 block/CU, 16 waves.
__global__ __launch_bounds__(1024, 4) void icnn_kernel(
    const float* __restrict__ state,
    const float* __restrict__ bz0, const float* __restrict__ bx0,
    const float* __restrict__ bx1, const float* __restrict__ bx2,
    const float* __restrict__ WzL, const float* __restrict__ WxL,
    u16* __restrict__ wsw, float* __restrict__ out) {
  __shared__ u16 zbA[BM * H];       // K-major activations, ping  (64 KB)
  __shared__ u16 zbB[BM * H];       // K-major activations, pong  (64 KB)
  __shared__ u16 xbuf[BM * 72];     // padded x staging, 9.2 KB

  const int tid = threadIdx.x;
  const int w = tid >> 6;           // 0..15
  const int lane = tid & 63;
  const int l15 = lane & 15;
  const int q = lane >> 4;
  const int blk = blockIdx.x;

  const u16* Wz0b = wsw + OFF_Wz0b;
  const u16* Wx0b = wsw + OFF_Wx0b;
  const u16* Wx1b = wsw + OFF_Wx1b;
  const u16* Wx2b = wsw + OFF_Wx2b;
  const u16* Wz1b = wsw + OFF_Wz1b;
  const u16* Wz2b = wsw + OFF_Wz2b;
  const u16* Wz3b = wsw + OFF_Wz3b;
  const u16* Wz1t = wsw + OFF_Wz1t;
  const u16* Wz2t = wsw + OFF_Wz2t;
  const u16* Wz3t = wsw + OFF_Wz3t;
  const u16* Wz0t = wsw + OFF_Wz0t;
  const u16* Wx0t = wsw + OFF_Wx0t;
  const u16* Wx1t = wsw + OFF_Wx1t;
  const u16* Wx2t = wsw + OFF_Wx2t;

  // LDS-only barrier: orders zbuf ds ops across waves; global loads/stores
  // stay in flight across it (no vmcnt drain).
  auto lbar = [&]() {
    asm volatile("s_waitcnt lgkmcnt(0)" ::: "memory");
    __builtin_amdgcn_s_barrier();
    asm volatile("" ::: "memory");
  };

  // ---- stage x = state-1 into xbuf (bf16, padded row-major) ----
  {
    int r = tid >> 4, c0 = (tid & 15) << 2;  // 64 rows x 16 chunks of 4 floats
    const float* p = state + (blk * BM + r) * D + c0;
    f32x4 v = __builtin_nontemporal_load((const f32x4*)p);
    u32* dst = (u32*)&xbuf[r * 72 + c0];
    dst[0] = (u32)f2bc(v[0] - 1.0f) | ((u32)f2bc(v[1] - 1.0f) << 16);
    dst[1] = (u32)f2bc(v[2] - 1.0f) | ((u32)f2bc(v[3] - 1.0f) << 16);
  }

  f32x4 acc[4][2];                  // 32 acc regs: 64 rows x 32 cols / wave
  const f32x4 Z = {0.f, 0.f, 0.f, 0.f};
  f32x4 pk = Z;                     // grad park: wave's single 16x16 out tile
  u64 sg0[8], sg1[8], sg2[8];       // register-resident sigmoids, 48 VGPRs

  // K-major zbuf reads: A-frag (row tile mt, K-step st): lane(q,l15) needs
  // z[mt*16+l15][st*32+q*8..+8] -> offset (st*4+mt)*512 + q*128 + l15*8.
  // 64 lanes cover one contiguous 1KB span: zero bank conflicts.
  auto ldA = [&](const u16* zb, int mt, int step) -> bf16x8 {
    return *(const bf16x8*)(&zb[(step * 4 + mt) * 512 + q * 128 + l15 * 8]);
  };
  auto ldX = [&](int mt, int ks) -> bf16x8 {       // x A-frag from padded xbuf
    return *(const bf16x8*)(&xbuf[(mt * 16 + l15) * 72 + ks * 32 + q * 8]);
  };
  auto wrZ = [&](u16* zb, int row, int n, u16 bits) {  // K-major scatter write
    zb[((n >> 5) * 4 + (row >> 4)) * 512 + ((n >> 3) & 3) * 128 +
       (row & 15) * 8 + (n & 7)] = bits;
  };
  auto zeroAcc = [&]() {
#pragma unroll
    for (int mt = 0; mt < 4; ++mt)
#pragma unroll
      for (int nt = 0; nt < 2; ++nt) acc[mt][nt] = Z;
  };

  // acc = x @ Wx^T (K=64), zero-start. Wx streams global->VGPR.
  auto fwdX = [&](const u16* Wxp) {
    const u16* xb = Wxp + lane * 8;
#pragma unroll
    for (int ks = 0; ks < 2; ++ks) {
      bf16x8 b2[2];
#pragma unroll
      for (int nt = 0; nt < 2; ++nt)
        b2[nt] = *(const bf16x8*)(xb + ((w * 2 + nt) * 2 + ks) * 512);
#pragma unroll
      for (int mt = 0; mt < 4; ++mt) {
        bf16x8 ax = ldX(mt, ks);
#pragma unroll
        for (int nt = 0; nt < 2; ++nt) {
          f32x4 c = (ks == 0) ? Z : acc[mt][nt];
          acc[mt][nt] = __builtin_amdgcn_mfma_f32_16x16x32_bf16(ax, b2[nt], c, 0, 0, 0);
        }
      }
    }
  };

  // acc += zb @ W^T (K=512), ALWAYS accumulating (callers zeroAcc first
  // if needed). B streams global->VGPR with depth-1 rotation; unroll 2
  // lets regalloc 2-color bc/bn so the rotation movs vanish.
  auto fwdH = [&](const u16* Wp, const u16* zb) {
    const u16* gb = Wp + (w * 2 * 16) * 512 + lane * 8;
    bf16x8 bc0 = *(const bf16x8*)(gb);
    bf16x8 bc1 = *(const bf16x8*)(gb + 16 * 512);
#pragma unroll 2
    for (int st = 0; st < 16; ++st) {
      int stn = (st < 15) ? st + 1 : st;     // clamp: harmless re-read at tail
      bf16x8 bn0 = *(const bf16x8*)(gb + stn * 512);
      bf16x8 bn1 = *(const bf16x8*)(gb + (16 + stn) * 512);
      bf16x8 a[4];
#pragma unroll
      for (int mt = 0; mt < 4; ++mt) a[mt] = ldA(zb, mt, st);
#pragma unroll
      for (int mt = 0; mt < 4; ++mt)
        acc[mt][0] = __builtin_amdgcn_mfma_f32_16x16x32_bf16(
            a[mt], bc0, acc[mt][0], 0, 0, 0);
#pragma unroll
      for (int mt = 0; mt < 4; ++mt)
        acc[mt][1] = __builtin_amdgcn_mfma_f32_16x16x32_bf16(
            a[mt], bc1, acc[mt][1], 0, 0, 0);
      bc0 = bn0; bc1 = bn1;
    }
  };

  // forward epilogue: a+=bias; z=softplus -> zb; s=sigmoid -> sg (registers)
  auto fwd_epi = [&](const float* biasp, u64 (&sg)[8], u16* zb) {
    float bias[2];
#pragma unroll
    for (int nt = 0; nt < 2; ++nt) bias[nt] = biasp[(w * 2 + nt) * 16 + l15];
#pragma unroll
    for (int mt = 0; mt < 4; ++mt)
#pragma unroll
      for (int nt = 0; nt < 2; ++nt) {
        int n = (w * 2 + nt) * 16 + l15;
        f32x4 A = acc[mt][nt];
        u64 pack = 0;
#pragma unroll
        for (int r = 0; r < 4; ++r) {
          float a = A[r] + bias[nt];
          float t = __expf(-a);
          float u = 1.0f + t;
          float s = __builtin_amdgcn_rcpf(u);     // sigmoid(a)
          float z = a + __logf(u);                // softplus(a)
          pack |= (u64)f2bc(s) << (16 * r);
          wrZ(zb, mt * 16 + q * 4 + r, n, f2bc(z));
        }
        sg[mt * 2 + nt] = pack;                   // static index (full unroll)
      }
  };
  auto d3_epi = [&](const float* biasp, u16* zb) {  // d3 = WzL*sigmoid(a3)
    float bias[2], wl[2];
#pragma unroll
    for (int nt = 0; nt < 2; ++nt) {
      bias[nt] = biasp[(w * 2 + nt) * 16 + l15];
      wl[nt] = WzL[(w * 2 + nt) * 16 + l15];
    }
#pragma unroll
    for (int mt = 0; mt < 4; ++mt)
#pragma unroll
      for (int nt = 0; nt < 2; ++nt) {
        int n = (w * 2 + nt) * 16 + l15;
        f32x4 A = acc[mt][nt];
#pragma unroll
        for (int r = 0; r < 4; ++r) {
          float a = A[r] + bias[nt];
          float t = __expf(-a);
          float s = __builtin_amdgcn_rcpf(1.0f + t);
          wrZ(zb, mt * 16 + q * 4 + r, n, f2bc(wl[nt] * s));
        }
      }
  };
  // d = g * s -> zb (s from registers; same thread produced both)
  auto bwd_epi = [&](const u64 (&sg)[8], u16* zb) {
#pragma unroll
    for (int mt = 0; mt < 4; ++mt)
#pragma unroll
      for (int nt = 0; nt < 2; ++nt) {
        int n = (w * 2 + nt) * 16 + l15;
        f32x4 A = acc[mt][nt];
        u64 v = sg[mt * 2 + nt];                  // static index
#pragma unroll
        for (int r = 0; r < 4; ++r) {
          float s = b2f((u32)(v >> (16 * r)) & 0xffffu);
          wrZ(zb, mt * 16 + q * 4 + r, n, f2bc(A[r] * s));
        }
      }
  };

  // grad mini-phase: pk += zb(d) @ Wg (main acc is DEAD here).
  // 16 waves <-> 16 out tiles: wave w owns tile (rt=w&3, ct=w>>2).
  // unroll 4: caps hoisted g-loads at 4 frags (full unroll spilled in R5).
  auto minigrad = [&](const u16* Wg, const u16* zb, bool init) {
    int rt = w & 3, ct = w >> 2;
    const u16* gb = Wg + lane * 8;
    f32x4 t = init ? Z : pk;
#pragma unroll 4
    for (int st = 0; st < 16; ++st) {
      bf16x8 a = ldA(zb, rt, st);
      bf16x8 g = *(const bf16x8*)(gb + (ct * 16 + st) * 512);
      t = __builtin_amdgcn_mfma_f32_16x16x32_bf16(a, g, t, 0, 0, 0);
    }
    pk = t;
  };

  // ---------------- forward ----------------
  lbar();                                   // xbuf ready
  fwdX(Wz0b);                               // a0 = x@Wz0^T
  fwd_epi(bz0, sg0, zbA);                   // z0 -> zbA, s0 -> regs
  lbar();                                   // P0
  fwdX(Wx0b); fwdH(Wz1b, zbA);              // a1 = x@Wx0^T + z0@Wz1^T
  fwd_epi(bx0, sg1, zbB);                   // z1 -> zbB (zbA still readable)
  lbar();                                   // P1
  fwdX(Wx1b); fwdH(Wz2b, zbB);              // a2
  fwd_epi(bx1, sg2, zbA);                   // z2 -> zbA
  lbar();                                   // P2
  fwdX(Wx2b); fwdH(Wz3b, zbA);              // a3
  d3_epi(bx2, zbB);                         // d3 -> zbB
  lbar();                                   // P3
  // ---------------- backward ----------------
  minigrad(Wx2t, zbB, true);                // pk  = d3@Wx2t
  zeroAcc(); fwdH(Wz3t, zbB);               // acc = d3@Wz3
  bwd_epi(sg2, zbA);                        // d2 -> zbA
  lbar();                                   // P4
  minigrad(Wx1t, zbA, false);               // pk += d2@Wx1t
  zeroAcc(); fwdH(Wz2t, zbA);               // acc = d2@Wz2
  bwd_epi(sg1, zbB);                        // d1 -> zbB
  lbar();                                   // P5
  minigrad(Wx0t, zbB, false);               // pk += d1@Wx0t
  zeroAcc(); fwdH(Wz1t, zbB);               // acc = d1@Wz1
  bwd_epi(sg0, zbA);                        // d0 -> zbA
  lbar();                                   // P6
  // ---- final: out = d0@Wz0t + pk + WxL ----
  minigrad(Wz0t, zbA, false);               // pk += d0@Wz0t
  {
    int rt = w & 3, ct = w >> 2;
    float wx = WxL[ct * 16 + l15];
#pragma unroll
    for (int r = 0; r < 4; ++r) {
      int row = blk * BM + rt * 16 + q * 4 + r;
      out[row * D + ct * 16 + l15] = pk[r] + wx;
    }
  }
}

extern "C" void kernel_launch(void* const* d_in, const int* in_sizes, int n_in,
                              void* d_out, int out_size, void* d_ws, size_t ws_size,
                              hipStream_t stream) {
  const float* state = (const float*)d_in[0];
  const float* Wz0 = (const float*)d_in[1];
  const float* bz0 = (const float*)d_in[2];
  const float* Wz1 = (const float*)d_in[3];
  const float* Wz2 = (const float*)d_in[4];
  const float* Wz3 = (const float*)d_in[5];
  const float* WzL = (const float*)d_in[6];
  const float* Wx0 = (const float*)d_in[7];
  const float* bx0 = (const float*)d_in[8];
  const float* Wx1 = (const float*)d_in[9];
  const float* bx1 = (const float*)d_in[10];
  const float* Wx2 = (const float*)d_in[11];
  const float* bx2 = (const float*)d_in[12];
  const float* WxL = (const float*)d_in[13];

  if (ws_size < (size_t)WS_ELEMS * 2) {
    fill_sentinel<<<(out_size + 255) / 256, 256, 0, stream>>>((float*)d_out, out_size);
    return;
  }
  u16* wsw = (u16*)d_ws;
  prep_kernel<<<OFF_WEND / 256, 256, 0, stream>>>(Wz0, Wz1, Wz2, Wz3, Wx0, Wx1, Wx2, wsw);
  icnn_kernel<<<B_TOTAL / BM, 1024, 0, stream>>>(state, bz0, bx0, bx1, bx2, WzL, WxL,
                                                 wsw, (float*)d_out);
}

// Round 12
// 406.687 us; speedup vs baseline: 1.0988x; 1.0773x over previous
//
#include <hip/hip_runtime.h>

typedef unsigned short u16;
typedef unsigned int u32;
typedef unsigned long long u64;

#define B_TOTAL 65536
#define H 512
#define D 64
#define BM 64

typedef __bf16 bf16x8 __attribute__((ext_vector_type(8)));
typedef float f32x4 __attribute__((ext_vector_type(4)));

__device__ __forceinline__ u32 f2b(float f) {  // fp32 -> bf16 bits, RNE (sw)
  u32 u = __builtin_bit_cast(u32, f);
  return (u + 0x7fffu + ((u >> 16) & 1u)) >> 16;
}
__device__ __forceinline__ u16 f2bc(float f) { // fp32 -> bf16 bits via HW cvt
  return __builtin_bit_cast(u16, (__bf16)f);   // RNE; compiler pairs into
}                                              // v_cvt_pk_bf16_f32
__device__ __forceinline__ float b2f(u32 bits) {
  return __builtin_bit_cast(float, bits << 16);
}

// ---- workspace layout (bf16 element offsets) ----
// Weight regions are FRAGMENT-PACKED: for logical B-matrix M[NN][KK],
// packed[( (n>>4)*(KK/32) + (k>>5) )*512 + lane*8 + j] = M[n][k],
// n = ntile*16 + (lane&15), k = kstep*32 + (lane>>4)*8 + j.
#define OFF_Wz0b 0          /* [N=512][K=64]  fwd L0 */
#define OFF_Wx0b 32768
#define OFF_Wx1b 65536
#define OFF_Wx2b 98304
#define OFF_Wz1b 131072     /* [N=512][K=512] fwd */
#define OFF_Wz2b 393216
#define OFF_Wz3b 655360
#define OFF_Wz1t 917504     /* [N=512][K=512] transposed, bwd */
#define OFF_Wz2t 1179648
#define OFF_Wz3t 1441792
#define OFF_Wz0t 1703936    /* [N=64][K=512] transposed grad weights */
#define OFF_Wx0t 1736704
#define OFF_Wx1t 1769472
#define OFF_Wx2t 1802240
#define OFF_WEND 1835008
// Slabs deleted in R9 (sigmoids live in registers); workspace is weights only.
#define WS_ELEMS OFF_WEND

// ---- weight prep: fp32 -> bf16, fragment-packed (+ transposed variants) ----
__global__ __launch_bounds__(256) void prep_kernel(
    const float* __restrict__ Wz0, const float* __restrict__ Wz1,
    const float* __restrict__ Wz2, const float* __restrict__ Wz3,
    const float* __restrict__ Wx0, const float* __restrict__ Wx1,
    const float* __restrict__ Wx2, u16* __restrict__ wsb) {
  int i = blockIdx.x * 256 + threadIdx.x;   // grid exactly covers OFF_WEND
  const float* src;
  int NN, KK, trans, p;
  if (i < 131072) {                          // x-path fwd: [512][64] direct
    int r = i >> 15; p = i & 32767;
    src = (r == 0) ? Wz0 : (r == 1) ? Wx0 : (r == 2) ? Wx1 : Wx2;
    NN = 512; KK = 64; trans = 0;
  } else if (i < 917504) {                   // H fwd: [512][512] direct
    int j = i - 131072; int r = j >> 18; p = j & 262143;
    src = (r == 0) ? Wz1 : (r == 1) ? Wz2 : Wz3;
    NN = 512; KK = 512; trans = 0;
  } else if (i < 1703936) {                  // H bwd: transposed
    int j = i - 917504; int r = j >> 18; p = j & 262143;
    src = (r == 0) ? Wz1 : (r == 1) ? Wz2 : Wz3;
    NN = 512; KK = 512; trans = 1;
  } else {                                   // grad weights: [64][512] = W^T
    int j = i - 1703936; int r = j >> 15; p = j & 32767;
    src = (r == 0) ? Wz0 : (r == 1) ? Wx0 : (r == 2) ? Wx1 : Wx2;
    NN = 64; KK = 512; trans = 1;
  }
  int jj = p & 7, lane = (p >> 3) & 63, blk = p >> 9;
  int kt_sh = (KK == 64) ? 1 : 4;            // log2(KK/32)
  int ntile = blk >> kt_sh;
  int kstep = blk & ((1 << kt_sh) - 1);
  int n = ntile * 16 + (lane & 15);
  int k = kstep * 32 + ((lane >> 4) << 3) + jj;
  float v = trans ? src[k * NN + n] : src[n * KK + k];
  wsb[i] = (u16)f2b(v);
}

__global__ __launch_bounds__(256) void fill_sentinel(float* out, int n) {
  int i = blockIdx.x * 256 + threadIdx.x;
  if (i < n) out[i] = 12345.0f;   // unmistakable "workspace too small" marker
}

// ---- fully-fused ICNN fwd+bwd (single GEMM kernel) ----
// ROUND-11 (resubmit; previous run died to infra) = ROUND-10 (383us; MFMA
// 27.6 + VALU 35.9 -> ~37% no-issue stall is the largest term) + three
// stall cuts, no structural change:
//  (1) fwdH B-prefetch depth 2 (3 live levels, +16 VGPRs): the load feeding
//      step st issues ~2 iterations (>=200cy wall) ahead -> L2 latency
//      hidden (depth-1 gave only ~1 contended iteration ~100cy).
//  (2) minigrad's 16-deep DEPENDENT MFMA chain split into even/odd partial
//      accumulators (two 8-deep chains; fp reassociation only).
//  (3) s_setprio(1) around MFMA clusters (T5): merged phases give waves
//      role diversity (some in epilogue VALU, some in MFMA) -> bias CU
//      arbitration toward matrix-pipe-feeding waves.
// Carried: B weights stream global->VGPR (L2-resident), register-resident
// sigmoids sg0..2, ping-pong K-major zbuf (conflict-free ldA), 8 LDS-only
// barriers, col-split ownership (wave w: cols [w*32,+32), acc[4][2]),
// HW bf16 cvt. LDS = 2x64K zbuf + 9.2K xbuf = 137 KB, 1 block/CU, 16 waves.
__global__ __launch_bounds__(1024, 4) void icnn_kernel(
    const float* __restrict__ state,
    const float* __restrict__ bz0, const float* __restrict__ bx0,
    const float* __restrict__ bx1, const float* __restrict__ bx2,
    const float* __restrict__ WzL, const float* __restrict__ WxL,
    u16* __restrict__ wsw, float* __restrict__ out) {
  __shared__ u16 zbA[BM * H];       // K-major activations, ping  (64 KB)
  __shared__ u16 zbB[BM * H];       // K-major activations, pong  (64 KB)
  __shared__ u16 xbuf[BM * 72];     // padded x staging, 9.2 KB

  const int tid = threadIdx.x;
  const int w = tid >> 6;           // 0..15
  const int lane = tid & 63;
  const int l15 = lane & 15;
  const int q = lane >> 4;
  const int blk = blockIdx.x;

  const u16* Wz0b = wsw + OFF_Wz0b;
  const u16* Wx0b = wsw + OFF_Wx0b;
  const u16* Wx1b = wsw + OFF_Wx1b;
  const u16* Wx2b = wsw + OFF_Wx2b;
  const u16* Wz1b = wsw + OFF_Wz1b;
  const u16* Wz2b = wsw + OFF_Wz2b;
  const u16* Wz3b = wsw + OFF_Wz3b;
  const u16* Wz1t = wsw + OFF_Wz1t;
  const u16* Wz2t = wsw + OFF_Wz2t;
  const u16* Wz3t = wsw + OFF_Wz3t;
  const u16* Wz0t = wsw + OFF_Wz0t;
  const u16* Wx0t = wsw + OFF_Wx0t;
  const u16* Wx1t = wsw + OFF_Wx1t;
  const u16* Wx2t = wsw + OFF_Wx2t;

  // LDS-only barrier: orders zbuf ds ops across waves; global loads/stores
  // stay in flight across it (no vmcnt drain).
  auto lbar = [&]() {
    asm volatile("s_waitcnt lgkmcnt(0)" ::: "memory");
    __builtin_amdgcn_s_barrier();
    asm volatile("" ::: "memory");
  };

  // ---- stage x = state-1 into xbuf (bf16, padded row-major) ----
  {
    int r = tid >> 4, c0 = (tid & 15) << 2;  // 64 rows x 16 chunks of 4 floats
    const float* p = state + (blk * BM + r) * D + c0;
    f32x4 v = __builtin_nontemporal_load((const f32x4*)p);
    u32* dst = (u32*)&xbuf[r * 72 + c0];
    dst[0] = (u32)f2bc(v[0] - 1.0f) | ((u32)f2bc(v[1] - 1.0f) << 16);
    dst[1] = (u32)f2bc(v[2] - 1.0f) | ((u32)f2bc(v[3] - 1.0f) << 16);
  }

  f32x4 acc[4][2];                  // 32 acc regs: 64 rows x 32 cols / wave
  const f32x4 Z = {0.f, 0.f, 0.f, 0.f};
  f32x4 pk = Z;                     // grad park: wave's single 16x16 out tile
  u64 sg0[8], sg1[8], sg2[8];       // register-resident sigmoids, 48 VGPRs

  // K-major zbuf reads: A-frag (row tile mt, K-step st): lane(q,l15) needs
  // z[mt*16+l15][st*32+q*8..+8] -> offset (st*4+mt)*512 + q*128 + l15*8.
  // 64 lanes cover one contiguous 1KB span: zero bank conflicts.
  auto ldA = [&](const u16* zb, int mt, int step) -> bf16x8 {
    return *(const bf16x8*)(&zb[(step * 4 + mt) * 512 + q * 128 + l15 * 8]);
  };
  auto ldX = [&](int mt, int ks) -> bf16x8 {       // x A-frag from padded xbuf
    return *(const bf16x8*)(&xbuf[(mt * 16 + l15) * 72 + ks * 32 + q * 8]);
  };
  auto wrZ = [&](u16* zb, int row, int n, u16 bits) {  // K-major scatter write
    zb[((n >> 5) * 4 + (row >> 4)) * 512 + ((n >> 3) & 3) * 128 +
       (row & 15) * 8 + (n & 7)] = bits;
  };
  auto zeroAcc = [&]() {
#pragma unroll
    for (int mt = 0; mt < 4; ++mt)
#pragma unroll
      for (int nt = 0; nt < 2; ++nt) acc[mt][nt] = Z;
  };

  // acc = x @ Wx^T (K=64), zero-start. Wx streams global->VGPR.
  auto fwdX = [&](const u16* Wxp) {
    const u16* xb = Wxp + lane * 8;
#pragma unroll
    for (int ks = 0; ks < 2; ++ks) {
      bf16x8 b2[2];
#pragma unroll
      for (int nt = 0; nt < 2; ++nt)
        b2[nt] = *(const bf16x8*)(xb + ((w * 2 + nt) * 2 + ks) * 512);
#pragma unroll
      for (int mt = 0; mt < 4; ++mt) {
        bf16x8 ax = ldX(mt, ks);
#pragma unroll
        for (int nt = 0; nt < 2; ++nt) {
          f32x4 c = (ks == 0) ? Z : acc[mt][nt];
          acc[mt][nt] = __builtin_amdgcn_mfma_f32_16x16x32_bf16(ax, b2[nt], c, 0, 0, 0);
        }
      }
    }
  };

  // acc += zb @ W^T (K=512), ALWAYS accumulating (callers zeroAcc first
  // if needed). B streams global->VGPR with DEPTH-2 rotation: the frags
  // consumed at step st were loaded at st-2 (>=2 contended iterations of
  // wall time) so the L2 ~200cy latency is covered. unroll 2 lets regalloc
  // rename the 2-level rotation away.
  auto fwdH = [&](const u16* Wp, const u16* zb) {
    const u16* gb = Wp + (w * 2 * 16) * 512 + lane * 8;
    bf16x8 b00 = *(const bf16x8*)(gb);                 // st+0
    bf16x8 b01 = *(const bf16x8*)(gb + 16 * 512);
    bf16x8 b10 = *(const bf16x8*)(gb + 512);           // st+1
    bf16x8 b11 = *(const bf16x8*)(gb + 17 * 512);
#pragma unroll 2
    for (int st = 0; st < 16; ++st) {
      int stp = (st < 14) ? st + 2 : st;   // prefetch st+2 (clamped re-read)
      bf16x8 bn0 = *(const bf16x8*)(gb + stp * 512);
      bf16x8 bn1 = *(const bf16x8*)(gb + (16 + stp) * 512);
      bf16x8 a[4];
#pragma unroll
      for (int mt = 0; mt < 4; ++mt) a[mt] = ldA(zb, mt, st);
      __builtin_amdgcn_s_setprio(1);
#pragma unroll
      for (int mt = 0; mt < 4; ++mt)
        acc[mt][0] = __builtin_amdgcn_mfma_f32_16x16x32_bf16(
            a[mt], b00, acc[mt][0], 0, 0, 0);
#pragma unroll
      for (int mt = 0; mt < 4; ++mt)
        acc[mt][1] = __builtin_amdgcn_mfma_f32_16x16x32_bf16(
            a[mt], b01, acc[mt][1], 0, 0, 0);
      __builtin_amdgcn_s_setprio(0);
      b00 = b10; b01 = b11; b10 = bn0; b11 = bn1;
    }
  };

  // forward epilogue: a+=bias; z=softplus -> zb; s=sigmoid -> sg (registers)
  auto fwd_epi = [&](const float* biasp, u64 (&sg)[8], u16* zb) {
    float bias[2];
#pragma unroll
    for (int nt = 0; nt < 2; ++nt) bias[nt] = biasp[(w * 2 + nt) * 16 + l15];
#pragma unroll
    for (int mt = 0; mt < 4; ++mt)
#pragma unroll
      for (int nt = 0; nt < 2; ++nt) {
        int n = (w * 2 + nt) * 16 + l15;
        f32x4 A = acc[mt][nt];
        u64 pack = 0;
#pragma unroll
        for (int r = 0; r < 4; ++r) {
          float a = A[r] + bias[nt];
          float t = __expf(-a);
          float u = 1.0f + t;
          float s = __builtin_amdgcn_rcpf(u);     // sigmoid(a)
          float z = a + __logf(u);                // softplus(a)
          pack |= (u64)f2bc(s) << (16 * r);
          wrZ(zb, mt * 16 + q * 4 + r, n, f2bc(z));
        }
        sg[mt * 2 + nt] = pack;                   // static index (full unroll)
      }
  };
  auto d3_epi = [&](const float* biasp, u16* zb) {  // d3 = WzL*sigmoid(a3)
    float bias[2], wl[2];
#pragma unroll
    for (int nt = 0; nt < 2; ++nt) {
      bias[nt] = biasp[(w * 2 + nt) * 16 + l15];
      wl[nt] = WzL[(w * 2 + nt) * 16 + l15];
    }
#pragma unroll
    for (int mt = 0; mt < 4; ++mt)
#pragma unroll
      for (int nt = 0; nt < 2; ++nt) {
        int n = (w * 2 + nt) * 16 + l15;
        f32x4 A = acc[mt][nt];
#pragma unroll
        for (int r = 0; r < 4; ++r) {
          float a = A[r] + bias[nt];
          float t = __expf(-a);
          float s = __builtin_amdgcn_rcpf(1.0f + t);
          wrZ(zb, mt * 16 + q * 4 + r, n, f2bc(wl[nt] * s));
        }
      }
  };
  // d = g * s -> zb (s from registers; same thread produced both)
  auto bwd_epi = [&](const u64 (&sg)[8], u16* zb) {
#pragma unroll
    for (int mt = 0; mt < 4; ++mt)
#pragma unroll
      for (int nt = 0; nt < 2; ++nt) {
        int n = (w * 2 + nt) * 16 + l15;
        f32x4 A = acc[mt][nt];
        u64 v = sg[mt * 2 + nt];                  // static index
#pragma unroll
        for (int r = 0; r < 4; ++r) {
          float s = b2f((u32)(v >> (16 * r)) & 0xffffu);
          wrZ(zb, mt * 16 + q * 4 + r, n, f2bc(A[r] * s));
        }
      }
  };

  // grad mini-phase: pk += zb(d) @ Wg (main acc is DEAD here).
  // 16 waves <-> 16 out tiles: wave w owns tile (rt=w&3, ct=w>>2).
  // Chain split even/odd: two 8-deep independent MFMA chains instead of
  // one 16-deep dependent chain (latency, not throughput, bound before).
  auto minigrad = [&](const u16* Wg, const u16* zb, bool init) {
    int rt = w & 3, ct = w >> 2;
    const u16* gb = Wg + lane * 8;
    f32x4 ta = init ? Z : pk, tb = Z;
#pragma unroll 2
    for (int st = 0; st < 16; st += 2) {
      bf16x8 a0 = ldA(zb, rt, st);
      bf16x8 g0 = *(const bf16x8*)(gb + (ct * 16 + st) * 512);
      bf16x8 a1 = ldA(zb, rt, st + 1);
      bf16x8 g1 = *(const bf16x8*)(gb + (ct * 16 + st + 1) * 512);
      __builtin_amdgcn_s_setprio(1);
      ta = __builtin_amdgcn_mfma_f32_16x16x32_bf16(a0, g0, ta, 0, 0, 0);
      tb = __builtin_amdgcn_mfma_f32_16x16x32_bf16(a1, g1, tb, 0, 0, 0);
      __builtin_amdgcn_s_setprio(0);
    }
    pk = ta + tb;
  };

  // ---------------- forward ----------------
  lbar();                                   // xbuf ready
  fwdX(Wz0b);                               // a0 = x@Wz0^T
  fwd_epi(bz0, sg0, zbA);                   // z0 -> zbA, s0 -> regs
  lbar();                                   // P0
  fwdX(Wx0b); fwdH(Wz1b, zbA);              // a1 = x@Wx0^T + z0@Wz1^T
  fwd_epi(bx0, sg1, zbB);                   // z1 -> zbB (zbA still readable)
  lbar();                                   // P1
  fwdX(Wx1b); fwdH(Wz2b, zbB);              // a2
  fwd_epi(bx1, sg2, zbA);                   // z2 -> zbA
  lbar();                                   // P2
  fwdX(Wx2b); fwdH(Wz3b, zbA);              // a3
  d3_epi(bx2, zbB);                         // d3 -> zbB
  lbar();                                   // P3
  // ---------------- backward ----------------
  minigrad(Wx2t, zbB, true);                // pk  = d3@Wx2t
  zeroAcc(); fwdH(Wz3t, zbB);               // acc = d3@Wz3
  bwd_epi(sg2, zbA);                        // d2 -> zbA
  lbar();                                   // P4
  minigrad(Wx1t, zbA, false);               // pk += d2@Wx1t
  zeroAcc(); fwdH(Wz2t, zbA);               // acc = d2@Wz2
  bwd_epi(sg1, zbB);                        // d1 -> zbB
  lbar();                                   // P5
  minigrad(Wx0t, zbB, false);               // pk += d1@Wx0t
  zeroAcc(); fwdH(Wz1t, zbB);               // acc = d1@Wz1
  bwd_epi(sg0, zbA);                        // d0 -> zbA
  lbar();                                   // P6
  // ---- final: out = d0@Wz0t + pk + WxL ----
  minigrad(Wz0t, zbA, false);               // pk += d0@Wz0t
  {
    int rt = w & 3, ct = w >> 2;
    float wx = WxL[ct * 16 + l15];
#pragma unroll
    for (int r = 0; r < 4; ++r) {
      int row = blk * BM + rt * 16 + q * 4 + r;
      out[row * D + ct * 16 + l15] = pk[r] + wx;
    }
  }
}

extern "C" void kernel_launch(void* const* d_in, const int* in_sizes, int n_in,
                              void* d_out, int out_size, void* d_ws, size_t ws_size,
                              hipStream_t stream) {
  const float* state = (const float*)d_in[0];
  const float* Wz0 = (const float*)d_in[1];
  const float* bz0 = (const float*)d_in[2];
  const float* Wz1 = (const float*)d_in[3];
  const float* Wz2 = (const float*)d_in[4];
  const float* Wz3 = (const float*)d_in[5];
  const float* WzL = (const float*)d_in[6];
  const float* Wx0 = (const float*)d_in[7];
  const float* bx0 = (const float*)d_in[8];
  const float* Wx1 = (const float*)d_in[9];
  const float* bx1 = (const float*)d_in[10];
  const float* Wx2 = (const float*)d_in[11];
  const float* bx2 = (const float*)d_in[12];
  const float* WxL = (const float*)d_in[13];

  if (ws_size < (size_t)WS_ELEMS * 2) {
    fill_sentinel<<<(out_size + 255) / 256, 256, 0, stream>>>((float*)d_out, out_size);
    return;
  }
  u16* wsw = (u16*)d_ws;
  prep_kernel<<<OFF_WEND / 256, 256, 0, stream>>>(Wz0, Wz1, Wz2, Wz3, Wx0, Wx1, Wx2, wsw);
  icnn_kernel<<<B_TOTAL / BM, 1024, 0, stream>>>(state, bz0, bx0, bx1, bx2, WzL, WxL,
                                                 wsw, (float*)d_out);
}